// Round 15
// baseline (52.475 us; speedup 1.0000x reference)
//
#include <hip/hip_runtime.h>

// Dynamic lightweight convolution. B=8, S=2048, D=1024, K=7, H=16, L=2042.
// R15: TL=8, 256-thread blocks, 8 blocks/CU for cross-block phase interleave.
//   stage x rows l0+6..l0+13 (bf16, XOR-swz, 16KB) -> 4 waves x 2 n-tiles MFMA
//   (A-frag shared) -> Lg f32 -> in-place softmax -> conv (R11 pattern: b64
//   bf16 x from LDS, f32 halo from global, f32x4 P) -> store.
// XCD-bijective swizzle: batch b <-> XCD, consecutive lb share halo in L2.

#define KK 7
#define HH 16
#define DD 1024
#define SS 2048
#define LL 2042
#define NO 112
#define TL 8
#define WTF_BYTES (7 * 32 * 64 * 8 * 2)      // 229376

typedef __attribute__((ext_vector_type(8))) short bf16x8;
typedef __attribute__((ext_vector_type(4))) float f32x4;

__device__ __forceinline__ unsigned short f2bf(float f) {
    unsigned u = __builtin_bit_cast(unsigned, f);
    u += 0x7fffu + ((u >> 16) & 1u);         // RNE
    return (unsigned short)(u >> 16);
}
__device__ __forceinline__ unsigned bfpack(float lo, float hi) {
    return (unsigned)f2bf(lo) | ((unsigned)f2bf(hi) << 16);
}
__device__ __forceinline__ float bflo(unsigned u) {
    return __builtin_bit_cast(float, u << 16);
}
__device__ __forceinline__ float bfhi(unsigned u) {
    return __builtin_bit_cast(float, u & 0xffff0000u);
}

__global__ void wprep(const float* __restrict__ W, unsigned short* __restrict__ wtf) {
    const int bx = blockIdx.x;               // 0..223 = i*32 + ks
    const int lane = threadIdx.x;
    const int i = bx >> 5, ks = bx & 31;
    const int frow = lane & 15, fq = lane >> 4;
    const int col = i * 16 + frow;
    const int k0 = ks * 32 + fq * 8;
    unsigned p[4];
#pragma unroll
    for (int j = 0; j < 4; ++j) {
        float a = W[(size_t)(k0 + 2 * j) * NO + col];
        float b = W[(size_t)(k0 + 2 * j + 1) * NO + col];
        p[j] = bfpack(a, b);
    }
    *(uint4*)(wtf + (size_t)(bx * 64 + lane) * 8) = make_uint4(p[0], p[1], p[2], p[3]);
}

// LDS (20096 B):
//   A  bf16 [8][1024] XOR-swizzled (x rows l0+6..l0+13) @ 0 .. 16384
//   Lg f32 [8][116] @ 16384 .. 20096 ; P in-place after softmax
template <bool WSOK>
__global__ __launch_bounds__(256, 8)
void dlconv(const float* __restrict__ x, const float* __restrict__ W,
            const float* __restrict__ bias, const unsigned short* __restrict__ wtf,
            float* __restrict__ out)
{
    __shared__ __align__(16) unsigned char smem[20096];
    float* Lg = (float*)(smem + 16384);      // [8][116]
    const int t = threadIdx.x;

    // XCD-bijective remap of the 2048-block grid: flat = x + 256*y (dispatch
    // order); n = (flat&7)*256 + flat>>3 -> XCD k gets batch k, contiguous lb.
    const int flat = blockIdx.x + (blockIdx.y << 8);
    const int n = ((flat & 7) << 8) + (flat >> 3);
    const int lb = n & 255, b = n >> 8;
    const int l0 = lb * TL;
    const float* xb = x + (size_t)b * SS * DD;

    // ---- stage x rows l0+6..l0+13 -> LDS rows 0..7 (bf16, XOR-swizzled) ----
#pragma unroll
    for (int s = 0; s < 8; ++s) {
        int idx = t + 256 * s;               // 0..2047 = 8 rows x 256 float4
        int row = idx >> 8, c4 = idx & 255;
        int gr = l0 + 6 + row; gr = gr < SS ? gr : SS - 1;
        float4 v = *(const float4*)(xb + (size_t)gr * DD + c4 * 4);
        int addr = row * 2048 + ((c4 * 8) ^ (row << 4));
        *(uint2*)(smem + addr) = make_uint2(bfpack(v.x, v.y), bfpack(v.z, v.w));
    }
    __syncthreads();                          // B1

    // ---- GEMM: wave w computes n-tiles w and w+4 (w<3); A-frag shared ----
    const int lane = t & 63, wid = t >> 6;
    const int frow = lane & 15, fq = lane >> 4;
    {
        const int ar = frow & 7;             // A row (rows 8..15 duplicate 0..7; C rows >=8 discarded)
        const int abase = ar * 2048;
        const int aswz = ar << 4;
        f32x4 acc0 = (f32x4)0.f, acc1 = (f32x4)0.f;
#pragma unroll 8
        for (int ks = 0; ks < 32; ++ks) {
            bf16x8 af = *(const bf16x8*)(smem + abase + ((ks * 64 + fq * 16) ^ aswz));
            if constexpr (WSOK) {
                bf16x8 b0 = *(const bf16x8*)(wtf + (size_t)((wid * 32 + ks) * 64 + lane) * 8);
                acc0 = __builtin_amdgcn_mfma_f32_16x16x32_bf16(af, b0, acc0, 0, 0, 0);
                if (wid < 3) {
                    bf16x8 b1 = *(const bf16x8*)(wtf + (size_t)(((wid + 4) * 32 + ks) * 64 + lane) * 8);
                    acc1 = __builtin_amdgcn_mfma_f32_16x16x32_bf16(af, b1, acc1, 0, 0, 0);
                }
            } else {
                const float* wp0 = W + (size_t)(ks * 32 + fq * 8) * NO + wid * 16 + frow;
                bf16x8 b0 = bf16x8{(short)f2bf(wp0[0 * NO]), (short)f2bf(wp0[1 * NO]),
                                   (short)f2bf(wp0[2 * NO]), (short)f2bf(wp0[3 * NO]),
                                   (short)f2bf(wp0[4 * NO]), (short)f2bf(wp0[5 * NO]),
                                   (short)f2bf(wp0[6 * NO]), (short)f2bf(wp0[7 * NO])};
                acc0 = __builtin_amdgcn_mfma_f32_16x16x32_bf16(af, b0, acc0, 0, 0, 0);
                if (wid < 3) {
                    const float* wp1 = wp0 + 64;
                    bf16x8 b1 = bf16x8{(short)f2bf(wp1[0 * NO]), (short)f2bf(wp1[1 * NO]),
                                       (short)f2bf(wp1[2 * NO]), (short)f2bf(wp1[3 * NO]),
                                       (short)f2bf(wp1[4 * NO]), (short)f2bf(wp1[5 * NO]),
                                       (short)f2bf(wp1[6 * NO]), (short)f2bf(wp1[7 * NO])};
                    acc1 = __builtin_amdgcn_mfma_f32_16x16x32_bf16(af, b1, acc1, 0, 0, 0);
                }
            }
        }
        // logits (+bias) for C rows 0..7 only (fq<2)
        if (fq < 2) {
#pragma unroll
            for (int reg = 0; reg < 4; ++reg) {
                int r = fq * 4 + reg;
                Lg[r * 116 + wid * 16 + frow] = acc0[reg] + bias[wid * 16 + frow];
                if (wid < 3)
                    Lg[r * 116 + (wid + 4) * 16 + frow] = acc1[reg] + bias[(wid + 4) * 16 + frow];
            }
        }
    }
    __syncthreads();                          // B2

    // ---- softmax over k, in-place (t<128: r = t>>4, h = t&15) ----
    if (t < 128) {
        const int r = t >> 4, h = t & 15;
        float v[KK];
        float m = -1e30f;
#pragma unroll
        for (int i = 0; i < KK; ++i) {
            v[i] = Lg[r * 116 + i * 16 + h];
            m = fmaxf(m, v[i]);
        }
        float ssum = 0.f;
#pragma unroll
        for (int i = 0; i < KK; ++i) { v[i] = __expf(v[i] - m); ssum += v[i]; }
        float inv = 1.f / (7.f * ssum);       // fold mean's 1/7
#pragma unroll
        for (int i = 0; i < KK; ++i) Lg[r * 116 + i * 16 + h] = v[i] * inv;
    }
    __syncthreads();                          // B3

    // ---- conv: thread t = col-quad cc, rows 0..7; window rows 0..13 ----
    const int cc = t;                        // 0..255
    const int hs = (cc & 3) << 2;
    const int coff = cc * 8;                 // byte offset in an LDS row
    float* orow0 = out + ((size_t)b * LL + l0) * DD + cc * 4;
#pragma unroll
    for (int q = 0; q < 8; ++q) {
        if (l0 + q < LL) {
            f32x4 o = (f32x4)0.f;
#pragma unroll
            for (int k = 0; k < KK; ++k) {
                f32x4 pv = *(const f32x4*)(Lg + q * 116 + k * 16 + hs);
                if (q + k < 6) {
                    // halo rows l0..l0+5: f32 from global (L2-hot, staged by lb-1)
                    f32x4 g = *(const f32x4*)(xb + (size_t)(l0 + q + k) * DD + cc * 4);
                    o += pv * g;
                } else {
                    int rr = q + k - 6;      // LDS row 0..7
                    uint2 u = *(const uint2*)(smem + rr * 2048 + (coff ^ (rr << 4)));
                    f32x4 xv = { bflo(u.x), bfhi(u.x), bflo(u.y), bfhi(u.y) };
                    o += pv * xv;
                }
            }
            *(f32x4*)(orow0 + (size_t)q * DD) = o;
        }
    }
}

extern "C" void kernel_launch(void* const* d_in, const int* in_sizes, int n_in,
                              void* d_out, int out_size, void* d_ws, size_t ws_size,
                              hipStream_t stream) {
    const float* x    = (const float*)d_in[0];
    const float* W    = (const float*)d_in[1];
    const float* bias = (const float*)d_in[2];
    float* out        = (float*)d_out;
    dim3 grid(256, 8);                       // 2048 blocks = 8/CU
    const bool wsok = (ws_size >= (size_t)WTF_BYTES) && d_ws != nullptr;
    if (wsok) {
        unsigned short* wtf = (unsigned short*)d_ws;
        wprep<<<224, 64, 0, stream>>>(W, wtf);
        dlconv<true><<<grid, 256, 0, stream>>>(x, W, bias, wtf, out);
    } else {
        dlconv<false><<<grid, 256, 0, stream>>>(x, W, bias, nullptr, out);
    }
}

// Round 16
// 39.746 us; speedup vs baseline: 1.3203x; 1.3203x over previous
//
#include <hip/hip_runtime.h>

// Dynamic lightweight convolution. B=8, S=2048, D=1024, K=7, H=16, L=2042.
// R16 = R13 with launch_bounds(512,4): the (512,8) bound clamped VGPR to 32
// and forced the 14-entry x-window to scratch (R12/R13 regressions). R14
// proved (512,4) frees the allocator (VGPR 60, no spill).
//   stage x rows l0+6..l0+21 (bf16, XOR-swz, 32KB) -> waves 0..6 MFMA one
//   n-tile -> Lg f32 -> softmax (regs) -> P2 bf16 overlay -> conv:
//   x window hoisted to 14 uint2 regs (template<RG>, straight-line), P2 b64
//   broadcast reads, store out.

#define KK 7
#define HH 16
#define DD 1024
#define SS 2048
#define LL 2042
#define NO 112
#define TL 16
#define WTF_BYTES (7 * 32 * 64 * 8 * 2)      // 229376
#define P2OFF 32768                           // P2 bf16 [16][4][7][4] = 3584 B

typedef __attribute__((ext_vector_type(8))) short bf16x8;
typedef __attribute__((ext_vector_type(4))) float f32x4;

__device__ __forceinline__ unsigned short f2bf(float f) {
    unsigned u = __builtin_bit_cast(unsigned, f);
    u += 0x7fffu + ((u >> 16) & 1u);         // RNE
    return (unsigned short)(u >> 16);
}
__device__ __forceinline__ unsigned bfpack(float lo, float hi) {
    return (unsigned)f2bf(lo) | ((unsigned)f2bf(hi) << 16);
}
__device__ __forceinline__ float bflo(unsigned u) {
    return __builtin_bit_cast(float, u << 16);
}
__device__ __forceinline__ float bfhi(unsigned u) {
    return __builtin_bit_cast(float, u & 0xffff0000u);
}

__global__ void wprep(const float* __restrict__ W, unsigned short* __restrict__ wtf) {
    const int bx = blockIdx.x;               // 0..223 = i*32 + ks
    const int lane = threadIdx.x;
    const int i = bx >> 5, ks = bx & 31;
    const int frow = lane & 15, fq = lane >> 4;
    const int col = i * 16 + frow;
    const int k0 = ks * 32 + fq * 8;
    unsigned p[4];
#pragma unroll
    for (int j = 0; j < 4; ++j) {
        float a = W[(size_t)(k0 + 2 * j) * NO + col];
        float b = W[(size_t)(k0 + 2 * j + 1) * NO + col];
        p[j] = bfpack(a, b);
    }
    *(uint4*)(wtf + (size_t)(bx * 64 + lane) * 8) = make_uint4(p[0], p[1], p[2], p[3]);
}

// Conv body: RG compile-time -> single-path init, static indexing throughout.
template <int RG>
__device__ __forceinline__ void conv_body(const unsigned char* smem, const float* xb,
                                          float* out, int l0, int b, int cc)
{
    const int coff = cc * 8;                 // byte offset in an LDS A row
    const int p2b = P2OFF + (cc & 3) * 56;
    float* orow0 = out + ((size_t)b * LL + l0) * DD + cc * 4;

    uint2 xw[14];
    if constexpr (RG == 0) {
        // window rows l0..l0+13: first 6 from global f32 (L2/L3-hot), rest LDS
#pragma unroll
        for (int j = 0; j < 6; ++j) {
            f32x4 g = *(const f32x4*)(xb + (size_t)(l0 + j) * DD + cc * 4);
            xw[j] = make_uint2(bfpack(g.x, g.y), bfpack(g.z, g.w));
        }
#pragma unroll
        for (int j = 6; j < 14; ++j) {
            int rr = j - 6;
            xw[j] = *(const uint2*)(smem + rr * 2048 + (coff ^ ((rr & 7) << 4)));
        }
    } else {
        // window rows l0+8..l0+21 = LDS rows 2..15
#pragma unroll
        for (int j = 0; j < 14; ++j) {
            int rr = j + 2;
            xw[j] = *(const uint2*)(smem + rr * 2048 + (coff ^ ((rr & 7) << 4)));
        }
    }
#pragma unroll
    for (int q = 0; q < 8; ++q) {
        const int row = RG * 8 + q;
        bool ok = (RG == 0) ? true : (l0 + row < LL);
        if (ok) {
            f32x4 o = (f32x4)0.f;
#pragma unroll
            for (int k = 0; k < KK; ++k) {
                uint2 pp = *(const uint2*)(smem + p2b + row * 224 + k * 8);
                uint2 u = xw[q + k];          // compile-time index
                o.x += bflo(pp.x) * bflo(u.x);
                o.y += bfhi(pp.x) * bfhi(u.x);
                o.z += bflo(pp.y) * bflo(u.y);
                o.w += bfhi(pp.y) * bfhi(u.y);
            }
            *(f32x4*)(orow0 + (size_t)row * DD) = o;
        }
    }
}

// LDS (40192 B):
//   A  bf16 [16][1024] XOR-swizzled (x rows l0+6..l0+21) @ 0 .. 32768
//   Lg f32 [16][116] @ 32768 .. 40192
//   P2 bf16 [16][4][7][4] @ 32768 .. 36352 (overlay, after B3 read-barrier)
template <bool WSOK>
__global__ __launch_bounds__(512, 4)
void dlconv(const float* __restrict__ x, const float* __restrict__ W,
            const float* __restrict__ bias, const unsigned short* __restrict__ wtf,
            float* __restrict__ out)
{
    __shared__ __align__(16) unsigned char smem[40192];
    float* Lg = (float*)(smem + 32768);      // [16][116]
    const int t  = threadIdx.x;
    const int lb = blockIdx.x, b = blockIdx.y;
    const int l0 = lb * TL;
    const float* xb = x + (size_t)b * SS * DD;

    // ---- stage x rows l0+6..l0+21 -> LDS rows 0..15 (bf16, XOR-swizzled) ----
#pragma unroll
    for (int s = 0; s < 8; ++s) {
        int idx = t + 512 * s;               // 0..4095 = 16 rows x 256 float4
        int row = idx >> 8, c4 = idx & 255;
        int gr = l0 + 6 + row; gr = gr < SS ? gr : SS - 1;
        float4 v = *(const float4*)(xb + (size_t)gr * DD + c4 * 4);
        int addr = row * 2048 + ((c4 * 8) ^ ((row & 7) << 4));
        *(uint2*)(smem + addr) = make_uint2(bfpack(v.x, v.y), bfpack(v.z, v.w));
    }
    __syncthreads();                          // B1

    // ---- GEMM: wave i (i<7) computes n-tile i (softmax index k=i) ----
    const int lane = t & 63, wid = t >> 6;
    const int frow = lane & 15, fq = lane >> 4;
    if (wid < 7) {
        const int abase = frow * 2048;
        const int aswz = (frow & 7) << 4;
        f32x4 acc = (f32x4)0.f;
#pragma unroll 8
        for (int ks = 0; ks < 32; ++ks) {
            bf16x8 af = *(const bf16x8*)(smem + abase + ((ks * 64 + fq * 16) ^ aswz));
            bf16x8 bf;
            if constexpr (WSOK) {
                bf = *(const bf16x8*)(wtf + (size_t)((wid * 32 + ks) * 64 + lane) * 8);
            } else {
                const float* wp = W + (size_t)(ks * 32 + fq * 8) * NO + wid * 16 + frow;
                short e0 = (short)f2bf(wp[0 * NO]), e1 = (short)f2bf(wp[1 * NO]);
                short e2 = (short)f2bf(wp[2 * NO]), e3 = (short)f2bf(wp[3 * NO]);
                short e4 = (short)f2bf(wp[4 * NO]), e5 = (short)f2bf(wp[5 * NO]);
                short e6 = (short)f2bf(wp[6 * NO]), e7 = (short)f2bf(wp[7 * NO]);
                bf = bf16x8{e0, e1, e2, e3, e4, e5, e6, e7};
            }
            acc = __builtin_amdgcn_mfma_f32_16x16x32_bf16(af, bf, acc, 0, 0, 0);
        }
        float bi = bias[wid * 16 + frow];
#pragma unroll
        for (int reg = 0; reg < 4; ++reg)
            Lg[(fq * 4 + reg) * 116 + wid * 16 + frow] = acc[reg] + bi;
    }
    __syncthreads();                          // B2

    // ---- softmax over k: read Lg -> regs ; bar ; write P2 bf16 overlay ----
    float v[KK];
    const int sr = t >> 4, sh = t & 15;
    if (t < 256) {
        float m = -1e30f;
#pragma unroll
        for (int i = 0; i < KK; ++i) {
            v[i] = Lg[sr * 116 + i * 16 + sh];
            m = fmaxf(m, v[i]);
        }
        float ssum = 0.f;
#pragma unroll
        for (int i = 0; i < KK; ++i) { v[i] = __expf(v[i] - m); ssum += v[i]; }
        float inv = 1.f / (7.f * ssum);       // fold mean's 1/7
#pragma unroll
        for (int i = 0; i < KK; ++i) v[i] *= inv;
    }
    __syncthreads();                          // B3: all Lg reads done
    if (t < 256) {
        const int pbase = P2OFF + sr * 224 + (sh >> 2) * 56 + (sh & 3) * 2;
#pragma unroll
        for (int i = 0; i < KK; ++i)
            *(unsigned short*)(smem + pbase + i * 8) = f2bf(v[i]);
    }
    __syncthreads();                          // B4

    // ---- conv, wave-uniform split; template kills the merged-array phi ----
    const int cc = t & 255;
    if ((t >> 8) == 0) conv_body<0>(smem, xb, out, l0, b, cc);
    else               conv_body<1>(smem, xb, out, l0, b, cc);
}

extern "C" void kernel_launch(void* const* d_in, const int* in_sizes, int n_in,
                              void* d_out, int out_size, void* d_ws, size_t ws_size,
                              hipStream_t stream) {
    const float* x    = (const float*)d_in[0];
    const float* W    = (const float*)d_in[1];
    const float* bias = (const float*)d_in[2];
    float* out        = (float*)d_out;
    dim3 grid((LL + TL - 1) / TL, 8);        // 128 x 8 = 1024 blocks
    const bool wsok = (ws_size >= (size_t)WTF_BYTES) && d_ws != nullptr;
    if (wsok) {
        unsigned short* wtf = (unsigned short*)d_ws;
        wprep<<<224, 64, 0, stream>>>(W, wtf);
        dlconv<true><<<grid, 512, 0, stream>>>(x, W, bias, wtf, out);
    } else {
        dlconv<false><<<grid, 512, 0, stream>>>(x, W, bias, nullptr, out);
    }
}

// Round 17
// 36.892 us; speedup vs baseline: 1.4224x; 1.0773x over previous
//
#include <hip/hip_runtime.h>

// Dynamic lightweight convolution. B=8, S=2048, D=1024, K=7, H=16, L=2042.
// R17 = R11 (best: 36.3us) + XCD-bijective block swizzle (b = flat&7 -> XCD k
// owns batch k with lb ascending, so conv halo rows -- staged by block lb-1 --
// hit the same XCD's L2 instead of cross-XCD L3).
//   stage x rows l0+6..l0+21 (bf16, XOR-swz, 32KB) -> waves 0..6 MFMA one
//   n-tile each -> logits Lg -> softmax IN-PLACE -> conv: x from LDS
//   (rows >= l0+6) or global f32 (rows l0..l0+5), P from Lg; store out.
// LDS 40192 B -> 4 blocks/CU; launch_bounds(512,8) -> VGPR 32, 32 waves/CU.

#define KK 7
#define HH 16
#define DD 1024
#define SS 2048
#define LL 2042
#define NO 112
#define TL 16
#define WTF_BYTES (7 * 32 * 64 * 8 * 2)      // 229376

typedef __attribute__((ext_vector_type(8))) short bf16x8;
typedef __attribute__((ext_vector_type(4))) float f32x4;

__device__ __forceinline__ unsigned short f2bf(float f) {
    unsigned u = __builtin_bit_cast(unsigned, f);
    u += 0x7fffu + ((u >> 16) & 1u);         // RNE
    return (unsigned short)(u >> 16);
}
__device__ __forceinline__ unsigned bfpack(float lo, float hi) {
    return (unsigned)f2bf(lo) | ((unsigned)f2bf(hi) << 16);
}
__device__ __forceinline__ float bflo(unsigned u) {
    return __builtin_bit_cast(float, u << 16);
}
__device__ __forceinline__ float bfhi(unsigned u) {
    return __builtin_bit_cast(float, u & 0xffff0000u);
}

__global__ void wprep(const float* __restrict__ W, unsigned short* __restrict__ wtf) {
    const int bx = blockIdx.x;               // 0..223 = i*32 + ks
    const int lane = threadIdx.x;
    const int i = bx >> 5, ks = bx & 31;
    const int frow = lane & 15, fq = lane >> 4;
    const int col = i * 16 + frow;
    const int k0 = ks * 32 + fq * 8;
    unsigned p[4];
#pragma unroll
    for (int j = 0; j < 4; ++j) {
        float a = W[(size_t)(k0 + 2 * j) * NO + col];
        float b = W[(size_t)(k0 + 2 * j + 1) * NO + col];
        p[j] = bfpack(a, b);
    }
    *(uint4*)(wtf + (size_t)(bx * 64 + lane) * 8) = make_uint4(p[0], p[1], p[2], p[3]);
}

// LDS (40192 B):
//   A  bf16 [16][1024] XOR-swizzled (x rows l0+6..l0+21) @ 0 .. 32768
//   Lg f32 [16][116] @ 32768 .. 40192 ; P overlaid in-place after softmax
template <bool WSOK>
__global__ __launch_bounds__(512, 8)
void dlconv(const float* __restrict__ x, const float* __restrict__ W,
            const float* __restrict__ bias, const unsigned short* __restrict__ wtf,
            float* __restrict__ out)
{
    __shared__ __align__(16) unsigned char smem[40192];
    float* Lg = (float*)(smem + 32768);      // [16][116]; becomes P in-place
    const int t  = threadIdx.x;

    // XCD-bijective swizzle: flat = lb + 128*b in dispatch order; XCD = flat%8.
    // Remap so XCD k runs batch k with lb ascending -> halo rows (staged by
    // lb-1 on the same XCD) are L2-hot.
    const int flat = blockIdx.x + (blockIdx.y << 7);
    const int b  = flat & 7;
    const int lb = flat >> 3;
    const int l0 = lb * TL;
    const float* xb = x + (size_t)b * SS * DD;

    // ---- stage x rows l0+6..l0+21 -> LDS rows 0..15 (bf16, XOR-swizzled) ----
#pragma unroll
    for (int s = 0; s < 8; ++s) {
        int idx = t + 512 * s;               // 0..4095 = 16 rows x 256 float4
        int row = idx >> 8, c4 = idx & 255;
        int gr = l0 + 6 + row; gr = gr < SS ? gr : SS - 1;
        float4 v = *(const float4*)(xb + (size_t)gr * DD + c4 * 4);
        int addr = row * 2048 + ((c4 * 8) ^ ((row & 7) << 4));
        *(uint2*)(smem + addr) = make_uint2(bfpack(v.x, v.y), bfpack(v.z, v.w));
    }
    __syncthreads();

    // ---- GEMM: wave i (i<7) computes n-tile i (softmax index k=i) ----
    const int lane = t & 63, wid = t >> 6;
    const int frow = lane & 15, fq = lane >> 4;
    if (wid < 7) {
        const int abase = frow * 2048;
        const int aswz = (frow & 7) << 4;
        f32x4 acc = (f32x4)0.f;
#pragma unroll 8
        for (int ks = 0; ks < 32; ++ks) {
            bf16x8 af = *(const bf16x8*)(smem + abase + ((ks * 64 + fq * 16) ^ aswz));
            bf16x8 bf;
            if constexpr (WSOK) {
                bf = *(const bf16x8*)(wtf + (size_t)((wid * 32 + ks) * 64 + lane) * 8);
            } else {
                const float* wp = W + (size_t)(ks * 32 + fq * 8) * NO + wid * 16 + frow;
                short e0 = (short)f2bf(wp[0 * NO]), e1 = (short)f2bf(wp[1 * NO]);
                short e2 = (short)f2bf(wp[2 * NO]), e3 = (short)f2bf(wp[3 * NO]);
                short e4 = (short)f2bf(wp[4 * NO]), e5 = (short)f2bf(wp[5 * NO]);
                short e6 = (short)f2bf(wp[6 * NO]), e7 = (short)f2bf(wp[7 * NO]);
                bf = bf16x8{e0, e1, e2, e3, e4, e5, e6, e7};
            }
            acc = __builtin_amdgcn_mfma_f32_16x16x32_bf16(af, bf, acc, 0, 0, 0);
        }
        float bi = bias[wid * 16 + frow];
#pragma unroll
        for (int reg = 0; reg < 4; ++reg)
            Lg[(fq * 4 + reg) * 116 + wid * 16 + frow] = acc[reg] + bi;
    }
    __syncthreads();

    // ---- softmax over k, in-place (thread owns its 7 slots; no extra bar) ----
    if (t < 256) {
        const int r = t >> 4, h = t & 15;
        float v[KK];
        float m = -1e30f;
#pragma unroll
        for (int i = 0; i < KK; ++i) {
            v[i] = Lg[r * 116 + i * 16 + h];
            m = fmaxf(m, v[i]);
        }
        float ssum = 0.f;
#pragma unroll
        for (int i = 0; i < KK; ++i) { v[i] = __expf(v[i] - m); ssum += v[i]; }
        float inv = 1.f / (7.f * ssum);       // fold mean's 1/7
#pragma unroll
        for (int i = 0; i < KK; ++i) Lg[r * 116 + i * 16 + h] = v[i] * inv;
    }
    __syncthreads();

    // ---- conv: out[b,l0+row,d] = sum_k P[row][k][d%16] * x[b,l0+row+k,d] ----
    const int rg = t >> 8;                   // wave-uniform
    const int cc = t & 255;
    const int hs = (cc & 3) << 2;
    const int coff = cc * 8;                 // byte offset in an LDS row
    float* orow0 = out + ((size_t)b * LL + l0) * DD + cc * 4;

    if (rg == 0) {
        f32x4 gx[6];
#pragma unroll
        for (int j = 0; j < 6; ++j)
            gx[j] = *(const f32x4*)(xb + (size_t)(l0 + j) * DD + cc * 4);
#pragma unroll
        for (int q = 0; q < 8; ++q) {
            f32x4 o = (f32x4)0.f;
#pragma unroll
            for (int k = 0; k < KK; ++k) {
                f32x4 pv = *(const f32x4*)(Lg + q * 116 + k * 16 + hs);
                if (q + k < 6) {
                    o += pv * gx[q + k];     // compile-time index
                } else {
                    int rr = q + k - 6;      // LDS row 0..9
                    uint2 u = *(const uint2*)(smem + rr * 2048 + (coff ^ ((rr & 7) << 4)));
                    f32x4 xv = { bflo(u.x), bfhi(u.x), bflo(u.y), bfhi(u.y) };
                    o += pv * xv;
                }
            }
            *(f32x4*)(orow0 + (size_t)q * DD) = o;
        }
    } else {
#pragma unroll
        for (int q = 0; q < 8; ++q) {
            int row = 8 + q;
            if (l0 + row < LL) {
                f32x4 o = (f32x4)0.f;
#pragma unroll
                for (int k = 0; k < KK; ++k) {
                    int rr = row + k - 6;    // LDS row 2..15
                    f32x4 pv = *(const f32x4*)(Lg + row * 116 + k * 16 + hs);
                    uint2 u = *(const uint2*)(smem + rr * 2048 + (coff ^ ((rr & 7) << 4)));
                    f32x4 xv = { bflo(u.x), bfhi(u.x), bflo(u.y), bfhi(u.y) };
                    o += pv * xv;
                }
                *(f32x4*)(orow0 + (size_t)row * DD) = o;
            }
        }
    }
}

extern "C" void kernel_launch(void* const* d_in, const int* in_sizes, int n_in,
                              void* d_out, int out_size, void* d_ws, size_t ws_size,
                              hipStream_t stream) {
    const float* x    = (const float*)d_in[0];
    const float* W    = (const float*)d_in[1];
    const float* bias = (const float*)d_in[2];
    float* out        = (float*)d_out;
    dim3 grid(128, 8);                       // 1024 blocks = 4/CU exactly
    const bool wsok = (ws_size >= (size_t)WTF_BYTES) && d_ws != nullptr;
    if (wsok) {
        unsigned short* wtf = (unsigned short*)d_ws;
        wprep<<<224, 64, 0, stream>>>(W, wtf);
        dlconv<true><<<grid, 512, 0, stream>>>(x, W, bias, wtf, out);
    } else {
        dlconv<false><<<grid, 512, 0, stream>>>(x, W, bias, nullptr, out);
    }
}